// Round 8
// baseline (24584.563 us; speedup 1.0000x reference)
//
#include <hip/hip_runtime.h>
#include <math.h>

#define A_PL 22
#define F_IN_ 16
#define T_LEN 256

__device__ __forceinline__ float sigmoidf_(float x) { return 1.f / (1.f + __expf(-x)); }

// seq_lengths: int64 or int32. True values in [128,256], never 0 =>
// little-endian int64 has lens32[1]==0.
__device__ __forceinline__ int read_len(const int* __restrict__ lens, int b) {
  return (lens[1] == 0) ? lens[2 * b] : lens[b];
}

// ---------------------------------------------------------------------------
// Kernel 1: NAIVE fused GAT1 (4 heads, concat) + GAT2 (1 head) + mean pool.
// One block per frame; every op is a flat idx-loop transcription of the
// reference einsums. No tiling, no register caching, no clever mappings.
// LDS: 352 + 2816 + 11264 + 528 = 14,960 floats = 59.8 KB.
// ---------------------------------------------------------------------------
__global__ __launch_bounds__(256) void gat_naive(
    const float* __restrict__ feat, const int* __restrict__ lens,
    const float* __restrict__ W1, const float* __restrict__ as1,
    const float* __restrict__ ad1, const float* __restrict__ b1,
    const float* __restrict__ W2, const float* __restrict__ as2,
    const float* __restrict__ ad2, const float* __restrict__ b2,
    float* __restrict__ pooled)
{
  const int n = blockIdx.x;
  const int tid = threadIdx.x;
  const int bb = n >> 8;          // batch
  const int tt = n & 255;         // time
  if (tt >= read_len(lens, bb)) { // masked frame: pooled = 0
    if (tid < 128) pooled[(size_t)n * 128 + tid] = 0.f;
    return;
  }

  __shared__ float xs[352];       // x [22][16]
  __shared__ float hbuf[2816];    // per-head h [22][128]; later h2 [22][128]
  __shared__ float x2s[11264];    // GAT1 output [22][512] (relu'd)
  __shared__ float asrc[22], adst[22], alpha[484];

  for (int i = tid; i < 352; i += 256) xs[i] = feat[(size_t)n * 352 + i];
  __syncthreads();

  // ================= GAT layer 1, head by head =================
  for (int hd = 0; hd < 4; hd++) {
    // h[a][c] = sum_f x[a][f] * W1[f][hd*128+c]
    for (int i = tid; i < 2816; i += 256) {
      int a = i >> 7, c = i & 127;
      float acc = 0.f;
      for (int f = 0; f < 16; f++) acc += xs[a * 16 + f] * W1[f * 512 + hd * 128 + c];
      hbuf[i] = acc;
    }
    __syncthreads();
    // a_src[a] = h[a,:].att_src[hd];  a_dst[a] = h[a,:].att_dst[hd]
    if (tid < 44) {
      int a = tid >> 1;
      const float* av = (tid & 1) ? ad1 : as1;
      float s = 0.f;
      for (int c = 0; c < 128; c++) s += hbuf[a * 128 + c] * av[hd * 128 + c];
      ((tid & 1) ? adst : asrc)[a] = s;
    }
    __syncthreads();
    // alpha[i][j] = softmax_j( leaky_relu(a_dst[i] + a_src[j], 0.2) )
    if (tid < 22) {
      float ev[22], m = -1e30f;
      for (int j = 0; j < 22; j++) {
        float e = adst[tid] + asrc[j];
        e = (e > 0.f) ? e : 0.2f * e;
        ev[j] = e; if (e > m) m = e;
      }
      float s = 0.f;
      for (int j = 0; j < 22; j++) { ev[j] = __expf(ev[j] - m); s += ev[j]; }
      float inv = 1.f / s;
      for (int j = 0; j < 22; j++) alpha[tid * 22 + j] = ev[j] * inv;
    }
    __syncthreads();
    // out[a][hd*128+c] = relu( sum_j alpha[a][j]*h[j][c] + b1[hd*128+c] )
    for (int i = tid; i < 2816; i += 256) {
      int a = i >> 7, c = i & 127;
      float acc = 0.f;
      for (int j = 0; j < 22; j++) acc += alpha[a * 22 + j] * hbuf[j * 128 + c];
      x2s[a * 512 + hd * 128 + c] = fmaxf(acc + b1[hd * 128 + c], 0.f);
    }
    __syncthreads();
  }

  // ================= GAT layer 2 (1 head) =================
  // h2[a][c] = sum_k x2[a][k] * W2[k][c]
  for (int i = tid; i < 2816; i += 256) {
    int a = i >> 7, c = i & 127;
    float acc = 0.f;
    for (int k = 0; k < 512; k++) acc += x2s[a * 512 + k] * W2[(size_t)k * 128 + c];
    hbuf[i] = acc;
  }
  __syncthreads();
  if (tid < 44) {
    int a = tid >> 1;
    const float* av = (tid & 1) ? ad2 : as2;
    float s = 0.f;
    for (int c = 0; c < 128; c++) s += hbuf[a * 128 + c] * av[c];
    ((tid & 1) ? adst : asrc)[a] = s;
  }
  __syncthreads();
  if (tid < 22) {
    float ev[22], m = -1e30f;
    for (int j = 0; j < 22; j++) {
      float e = adst[tid] + asrc[j];
      e = (e > 0.f) ? e : 0.2f * e;
      ev[j] = e; if (e > m) m = e;
    }
    float s = 0.f;
    for (int j = 0; j < 22; j++) { ev[j] = __expf(ev[j] - m); s += ev[j]; }
    float inv = 1.f / s;
    for (int j = 0; j < 22; j++) alpha[tid * 22 + j] = ev[j] * inv;
  }
  __syncthreads();
  // pooled[c] = mean_a relu( sum_j alpha[a][j]*h2[j][c] + b2[c] )
  if (tid < 128) {
    float s = 0.f;
    for (int a = 0; a < 22; a++) {
      float v = b2[tid];
      for (int j = 0; j < 22; j++) v += alpha[a * 22 + j] * hbuf[j * 128 + tid];
      s += fmaxf(v, 0.f);
    }
    pooled[(size_t)n * 128 + tid] = s * (1.f / 22.f);
  }
}

// ---------------------------------------------------------------------------
// Kernel 2: naive LSTM, one block per batch element (identical to R7).
// ---------------------------------------------------------------------------
__global__ __launch_bounds__(256) void lstm_batch(
    const float* __restrict__ pooled,
    const float* __restrict__ Wih0, const float* __restrict__ bih0,
    const float* __restrict__ bhh0, const float* __restrict__ Whh0,
    const float* __restrict__ Wih1, const float* __restrict__ Whh1,
    const float* __restrict__ bih1, const float* __restrict__ bhh1,
    const int* __restrict__ lens,
    const float* __restrict__ clfw, const float* __restrict__ clfb,
    float* __restrict__ out)
{
  const int b = blockIdx.x;
  const int j = threadIdx.x;

  __shared__ float h0[256], c0[256], h1[256], c1[256], xb[128], red[256];

  h0[j] = 0.f; c0[j] = 0.f; h1[j] = 0.f; c1[j] = 0.f;
  __syncthreads();

  const int len_b = read_len(lens, b);

  const float bA0 = bih0[j]       + bhh0[j];
  const float bA1 = bih0[256 + j] + bhh0[256 + j];
  const float bA2 = bih0[512 + j] + bhh0[512 + j];
  const float bA3 = bih0[768 + j] + bhh0[768 + j];
  const float bB0 = bih1[j]       + bhh1[j];
  const float bB1 = bih1[256 + j] + bhh1[256 + j];
  const float bB2 = bih1[512 + j] + bhh1[512 + j];
  const float bB3 = bih1[768 + j] + bhh1[768 + j];

  const float* wiA0 = Wih0 + (size_t)j * 128;
  const float* wiA1 = Wih0 + (size_t)(256 + j) * 128;
  const float* wiA2 = Wih0 + (size_t)(512 + j) * 128;
  const float* wiA3 = Wih0 + (size_t)(768 + j) * 128;
  const float* whA0 = Whh0 + (size_t)j * 256;
  const float* whA1 = Whh0 + (size_t)(256 + j) * 256;
  const float* whA2 = Whh0 + (size_t)(512 + j) * 256;
  const float* whA3 = Whh0 + (size_t)(768 + j) * 256;
  const float* wiB0 = Wih1 + (size_t)j * 256;
  const float* wiB1 = Wih1 + (size_t)(256 + j) * 256;
  const float* wiB2 = Wih1 + (size_t)(512 + j) * 256;
  const float* wiB3 = Wih1 + (size_t)(768 + j) * 256;
  const float* whB0 = Whh1 + (size_t)j * 256;
  const float* whB1 = Whh1 + (size_t)(256 + j) * 256;
  const float* whB2 = Whh1 + (size_t)(512 + j) * 256;
  const float* whB3 = Whh1 + (size_t)(768 + j) * 256;

  for (int t = 0; t < T_LEN; t++) {
    const bool valid = t < len_b;

    if (j < 128) xb[j] = pooled[(size_t)(b * 256 + t) * 128 + j];
    __syncthreads();

    // -------- layer 0 --------
    float g0 = bA0, g1 = bA1, g2 = bA2, g3 = bA3;
    for (int k4 = 0; k4 < 32; k4++) {
      int k = k4 * 4;
      float4 w0 = *(const float4*)(wiA0 + k);
      float4 w1 = *(const float4*)(wiA1 + k);
      float4 w2 = *(const float4*)(wiA2 + k);
      float4 w3 = *(const float4*)(wiA3 + k);
      float x0 = xb[k], x1 = xb[k + 1], x2 = xb[k + 2], x3 = xb[k + 3];
      g0 += x0 * w0.x + x1 * w0.y + x2 * w0.z + x3 * w0.w;
      g1 += x0 * w1.x + x1 * w1.y + x2 * w1.z + x3 * w1.w;
      g2 += x0 * w2.x + x1 * w2.y + x2 * w2.z + x3 * w2.w;
      g3 += x0 * w3.x + x1 * w3.y + x2 * w3.z + x3 * w3.w;
    }
    for (int k4 = 0; k4 < 64; k4++) {
      int k = k4 * 4;
      float4 w0 = *(const float4*)(whA0 + k);
      float4 w1 = *(const float4*)(whA1 + k);
      float4 w2 = *(const float4*)(whA2 + k);
      float4 w3 = *(const float4*)(whA3 + k);
      float x0 = h0[k], x1 = h0[k + 1], x2 = h0[k + 2], x3 = h0[k + 3];
      g0 += x0 * w0.x + x1 * w0.y + x2 * w0.z + x3 * w0.w;
      g1 += x0 * w1.x + x1 * w1.y + x2 * w1.z + x3 * w1.w;
      g2 += x0 * w2.x + x1 * w2.y + x2 * w2.z + x3 * w2.w;
      g3 += x0 * w3.x + x1 * w3.y + x2 * w3.z + x3 * w3.w;
    }
    {
      float iv = sigmoidf_(g0), fv = sigmoidf_(g1);
      float gv = tanhf(g2),     ov = sigmoidf_(g3);
      float cold = c0[j], hold = h0[j];
      float cnew = fv * cold + iv * gv;
      float hnew = ov * tanhf(cnew);
      __syncthreads();
      h0[j] = valid ? hnew : hold;
      c0[j] = valid ? cnew : cold;
      __syncthreads();
    }

    // -------- layer 1 --------
    float s0 = bB0, s1 = bB1, s2 = bB2, s3 = bB3;
    for (int k4 = 0; k4 < 64; k4++) {
      int k = k4 * 4;
      float4 w0 = *(const float4*)(wiB0 + k);
      float4 w1 = *(const float4*)(wiB1 + k);
      float4 w2 = *(const float4*)(wiB2 + k);
      float4 w3 = *(const float4*)(wiB3 + k);
      float x0 = h0[k], x1 = h0[k + 1], x2 = h0[k + 2], x3 = h0[k + 3];
      s0 += x0 * w0.x + x1 * w0.y + x2 * w0.z + x3 * w0.w;
      s1 += x0 * w1.x + x1 * w1.y + x2 * w1.z + x3 * w1.w;
      s2 += x0 * w2.x + x1 * w2.y + x2 * w2.z + x3 * w2.w;
      s3 += x0 * w3.x + x1 * w3.y + x2 * w3.z + x3 * w3.w;
    }
    for (int k4 = 0; k4 < 64; k4++) {
      int k = k4 * 4;
      float4 w0 = *(const float4*)(whB0 + k);
      float4 w1 = *(const float4*)(whB1 + k);
      float4 w2 = *(const float4*)(whB2 + k);
      float4 w3 = *(const float4*)(whB3 + k);
      float x0 = h1[k], x1 = h1[k + 1], x2 = h1[k + 2], x3 = h1[k + 3];
      s0 += x0 * w0.x + x1 * w0.y + x2 * w0.z + x3 * w0.w;
      s1 += x0 * w1.x + x1 * w1.y + x2 * w1.z + x3 * w1.w;
      s2 += x0 * w2.x + x1 * w2.y + x2 * w2.z + x3 * w2.w;
      s3 += x0 * w3.x + x1 * w3.y + x2 * w3.z + x3 * w3.w;
    }
    {
      float iv = sigmoidf_(s0), fv = sigmoidf_(s1);
      float gv = tanhf(s2),     ov = sigmoidf_(s3);
      float cold = c1[j], hold = h1[j];
      float cnew = fv * cold + iv * gv;
      float hnew = ov * tanhf(cnew);
      __syncthreads();
      h1[j] = valid ? hnew : hold;
      c1[j] = valid ? cnew : cold;
      __syncthreads();
    }
  }

  red[j] = h1[j] * clfw[j];
  __syncthreads();
  for (int s = 128; s > 0; s >>= 1) {
    if (j < s) red[j] += red[j + s];
    __syncthreads();
  }
  if (j == 0) out[b] = red[0] + clfb[0];
}

// ---------------------------------------------------------------------------
extern "C" void kernel_launch(void* const* d_in, const int* in_sizes, int n_in,
                              void* d_out, int out_size, void* d_ws, size_t ws_size,
                              hipStream_t stream) {
  (void)in_sizes; (void)n_in; (void)out_size; (void)ws_size;
  const float* feat = (const float*)d_in[0];
  const int*   lens = (const int*)d_in[1];
  const float* W1   = (const float*)d_in[2];
  const float* as1  = (const float*)d_in[3];
  const float* ad1  = (const float*)d_in[4];
  const float* b1   = (const float*)d_in[5];
  const float* W2   = (const float*)d_in[6];
  const float* as2  = (const float*)d_in[7];
  const float* ad2  = (const float*)d_in[8];
  const float* b2   = (const float*)d_in[9];
  const float* Wih0 = (const float*)d_in[10];
  const float* Whh0 = (const float*)d_in[11];
  const float* bih0 = (const float*)d_in[12];
  const float* bhh0 = (const float*)d_in[13];
  const float* Wih1 = (const float*)d_in[14];
  const float* Whh1 = (const float*)d_in[15];
  const float* bih1 = (const float*)d_in[16];
  const float* bhh1 = (const float*)d_in[17];
  const float* clfw = (const float*)d_in[18];
  const float* clfb = (const float*)d_in[19];

  float* pooled = (float*)d_ws;   // [8192][128] fp32 -> 4 MB ws use

  gat_naive<<<8192, 256, 0, stream>>>(feat, lens, W1, as1, ad1, b1,
                                      W2, as2, ad2, b2, pooled);
  lstm_batch<<<32, 256, 0, stream>>>(pooled, Wih0, bih0, bhh0, Whh0,
                                     Wih1, Whh1, bih1, bhh1,
                                     lens, clfw, clfb, (float*)d_out);
}

// Round 9
// 17808.154 us; speedup vs baseline: 1.3805x; 1.3805x over previous
//
#include <hip/hip_runtime.h>
#include <hip/hip_cooperative_groups.h>
#include <math.h>

namespace cg = cooperative_groups;

#define A_PL 22
#define F_IN_ 16
#define T_LEN 256
#define NBLK_SEQ 64

__device__ __forceinline__ float sigmoidf_(float x) { return 1.f / (1.f + __expf(-x)); }

// Cross-XCD-safe handoff (belt and braces on top of grid.sync fences).
__device__ __forceinline__ void gstore(float* p, float v) {
  __hip_atomic_store(p, v, __ATOMIC_RELAXED, __HIP_MEMORY_SCOPE_AGENT);
}
__device__ __forceinline__ float gload(const float* p) {
  return __hip_atomic_load(p, __ATOMIC_RELAXED, __HIP_MEMORY_SCOPE_AGENT);
}

// seq_lengths: int64 or int32. True values in [128,256], never 0 =>
// little-endian int64 has lens32[1]==0.
__device__ __forceinline__ int read_len(const int* __restrict__ lens, int b) {
  return (lens[1] == 0) ? lens[2 * b] : lens[b];
}

// ---------------------------------------------------------------------------
// Kernel 1: NAIVE fused GAT (proven correct in R8 — do not touch this round).
// ---------------------------------------------------------------------------
__global__ __launch_bounds__(256) void gat_naive(
    const float* __restrict__ feat, const int* __restrict__ lens,
    const float* __restrict__ W1, const float* __restrict__ as1,
    const float* __restrict__ ad1, const float* __restrict__ b1,
    const float* __restrict__ W2, const float* __restrict__ as2,
    const float* __restrict__ ad2, const float* __restrict__ b2,
    float* __restrict__ pooled)
{
  const int n = blockIdx.x;
  const int tid = threadIdx.x;
  const int bb = n >> 8;          // batch
  const int tt = n & 255;         // time
  if (tt >= read_len(lens, bb)) { // masked frame: pooled = 0
    if (tid < 128) pooled[(size_t)n * 128 + tid] = 0.f;
    return;
  }

  __shared__ float xs[352];       // x [22][16]
  __shared__ float hbuf[2816];    // per-head h [22][128]; later h2 [22][128]
  __shared__ float x2s[11264];    // GAT1 output [22][512] (relu'd)
  __shared__ float asrc[22], adst[22], alpha[484];

  for (int i = tid; i < 352; i += 256) xs[i] = feat[(size_t)n * 352 + i];
  __syncthreads();

  for (int hd = 0; hd < 4; hd++) {
    for (int i = tid; i < 2816; i += 256) {
      int a = i >> 7, c = i & 127;
      float acc = 0.f;
      for (int f = 0; f < 16; f++) acc += xs[a * 16 + f] * W1[f * 512 + hd * 128 + c];
      hbuf[i] = acc;
    }
    __syncthreads();
    if (tid < 44) {
      int a = tid >> 1;
      const float* av = (tid & 1) ? ad1 : as1;
      float s = 0.f;
      for (int c = 0; c < 128; c++) s += hbuf[a * 128 + c] * av[hd * 128 + c];
      ((tid & 1) ? adst : asrc)[a] = s;
    }
    __syncthreads();
    if (tid < 22) {
      float ev[22], m = -1e30f;
      for (int j = 0; j < 22; j++) {
        float e = adst[tid] + asrc[j];
        e = (e > 0.f) ? e : 0.2f * e;
        ev[j] = e; if (e > m) m = e;
      }
      float s = 0.f;
      for (int j = 0; j < 22; j++) { ev[j] = __expf(ev[j] - m); s += ev[j]; }
      float inv = 1.f / s;
      for (int j = 0; j < 22; j++) alpha[tid * 22 + j] = ev[j] * inv;
    }
    __syncthreads();
    for (int i = tid; i < 2816; i += 256) {
      int a = i >> 7, c = i & 127;
      float acc = 0.f;
      for (int j = 0; j < 22; j++) acc += alpha[a * 22 + j] * hbuf[j * 128 + c];
      x2s[a * 512 + hd * 128 + c] = fmaxf(acc + b1[hd * 128 + c], 0.f);
    }
    __syncthreads();
  }

  for (int i = tid; i < 2816; i += 256) {
    int a = i >> 7, c = i & 127;
    float acc = 0.f;
    for (int k = 0; k < 512; k++) acc += x2s[a * 512 + k] * W2[(size_t)k * 128 + c];
    hbuf[i] = acc;
  }
  __syncthreads();
  if (tid < 44) {
    int a = tid >> 1;
    const float* av = (tid & 1) ? ad2 : as2;
    float s = 0.f;
    for (int c = 0; c < 128; c++) s += hbuf[a * 128 + c] * av[c];
    ((tid & 1) ? adst : asrc)[a] = s;
  }
  __syncthreads();
  if (tid < 22) {
    float ev[22], m = -1e30f;
    for (int j = 0; j < 22; j++) {
      float e = adst[tid] + asrc[j];
      e = (e > 0.f) ? e : 0.2f * e;
      ev[j] = e; if (e > m) m = e;
    }
    float s = 0.f;
    for (int j = 0; j < 22; j++) { ev[j] = __expf(ev[j] - m); s += ev[j]; }
    float inv = 1.f / s;
    for (int j = 0; j < 22; j++) alpha[tid * 22 + j] = ev[j] * inv;
  }
  __syncthreads();
  if (tid < 128) {
    float s = 0.f;
    for (int a = 0; a < 22; a++) {
      float v = b2[tid];
      for (int j = 0; j < 22; j++) v += alpha[a * 22 + j] * hbuf[j * 128 + tid];
      s += fmaxf(v, 0.f);
    }
    pooled[(size_t)n * 128 + tid] = s * (1.f / 22.f);
  }
}

// ---------------------------------------------------------------------------
// Kernel 2: cooperative split-j LSTM. 64 blocks; block handles j-columns
// blockIdx*4..+3 for ALL 32 batches (weights L1-hot, broadcast across the
// 32 same-j lanes). Thread pair (half) split-K + __shfl_xor. h exchanged via
// ws + grid.sync(); h staged in LDS with (b+k)&31 swizzle (bank-conflict-free
// [k][b] reads). Layer-0 input gates computed on the fly from pooled.
// ---------------------------------------------------------------------------
__global__ __launch_bounds__(256) void lstm_seq(
    const float* __restrict__ pooled,
    const float* __restrict__ Wih0, const float* __restrict__ bih0,
    const float* __restrict__ bhh0, const float* __restrict__ Whh0,
    const float* __restrict__ Wih1, const float* __restrict__ Whh1,
    const float* __restrict__ bih1, const float* __restrict__ bhh1,
    const int* __restrict__ lens,
    const float* __restrict__ clfw, const float* __restrict__ clfb,
    float* __restrict__ ws, float* __restrict__ out)
{
  cg::grid_group grid = cg::this_grid();

  __shared__ float shx[8192];   // 32 KB
  __shared__ float shh[8192];   // 32 KB

  float* h0buf = ws + 64;              // [2][32][256]
  float* c0    = h0buf + 16384;        // [32][256]
  float* h1buf = c0 + 8192;            // [2][32][256]
  float* c1    = h1buf + 16384;        // [32][256]

  const int tid  = threadIdx.x;
  const int cell = tid >> 1;
  const int half = tid & 1;
  const int b    = cell & 31;
  const int jj   = cell >> 5;
  const int j    = blockIdx.x * 4 + jj;
  const int len_b = read_len(lens, b);

  const float bA0 = bih0[j]       + bhh0[j];
  const float bA1 = bih0[256 + j] + bhh0[256 + j];
  const float bA2 = bih0[512 + j] + bhh0[512 + j];
  const float bA3 = bih0[768 + j] + bhh0[768 + j];
  const float bB0 = bih1[j]       + bhh1[j];
  const float bB1 = bih1[256 + j] + bhh1[256 + j];
  const float bB2 = bih1[512 + j] + bhh1[512 + j];
  const float bB3 = bih1[768 + j] + bhh1[768 + j];

  const float* wA0 = Whh0 + (size_t)j * 256;
  const float* wA1 = Whh0 + (size_t)(256 + j) * 256;
  const float* wA2 = Whh0 + (size_t)(512 + j) * 256;
  const float* wA3 = Whh0 + (size_t)(768 + j) * 256;

  const float* wI0 = Wih0 + (size_t)j * 128         + half * 64;
  const float* wI1 = Wih0 + (size_t)(256 + j) * 128 + half * 64;
  const float* wI2 = Wih0 + (size_t)(512 + j) * 128 + half * 64;
  const float* wI3 = Wih0 + (size_t)(768 + j) * 128 + half * 64;

  for (int t = 0; t < T_LEN; t++) {
    const int cur = t & 1, prv = cur ^ 1;

    // ================= phase A: layer-0 step =================
    {
      const float* src = h0buf + prv * 8192;
      for (int i = tid; i < 8192; i += 256) {
        int bq = i >> 8, kq = i & 255;
        shx[kq * 32 + ((bq + kq) & 31)] = gload(src + i);
      }
    }
    __syncthreads();

    float a0 = 0.f, a1 = 0.f, a2 = 0.f, a3 = 0.f;
    {
      const int kbase = half * 128;
      for (int k4 = 0; k4 < 32; k4++) {
        int k = kbase + k4 * 4;
        float4 w0 = *(const float4*)(wA0 + k);
        float4 w1 = *(const float4*)(wA1 + k);
        float4 w2 = *(const float4*)(wA2 + k);
        float4 w3 = *(const float4*)(wA3 + k);
        #pragma unroll
        for (int u = 0; u < 4; u++) {
          int ku = k + u;
          float hv = shx[ku * 32 + ((b + ku) & 31)];
          a0 += hv * ((const float*)&w0)[u];
          a1 += hv * ((const float*)&w1)[u];
          a2 += hv * ((const float*)&w2)[u];
          a3 += hv * ((const float*)&w3)[u];
        }
      }
      const float* pp = pooled + ((size_t)(b * 256 + t)) * 128 + half * 64;
      for (int k4 = 0; k4 < 16; k4++) {
        float4 xv = *(const float4*)(pp + k4 * 4);
        float4 w0 = *(const float4*)(wI0 + k4 * 4);
        float4 w1 = *(const float4*)(wI1 + k4 * 4);
        float4 w2 = *(const float4*)(wI2 + k4 * 4);
        float4 w3 = *(const float4*)(wI3 + k4 * 4);
        a0 += xv.x * w0.x + xv.y * w0.y + xv.z * w0.z + xv.w * w0.w;
        a1 += xv.x * w1.x + xv.y * w1.y + xv.z * w1.z + xv.w * w1.w;
        a2 += xv.x * w2.x + xv.y * w2.y + xv.z * w2.z + xv.w * w2.w;
        a3 += xv.x * w3.x + xv.y * w3.y + xv.z * w3.z + xv.w * w3.w;
      }
    }
    a0 += __shfl_xor(a0, 1); a1 += __shfl_xor(a1, 1);
    a2 += __shfl_xor(a2, 1); a3 += __shfl_xor(a3, 1);

    {
      float iv = sigmoidf_(a0 + bA0);
      float fv = sigmoidf_(a1 + bA1);
      float gv = tanhf(a2 + bA2);
      float ov = sigmoidf_(a3 + bA3);
      float cold = c0[b * 256 + j];
      float cnew = fv * cold + iv * gv;
      float hnew = ov * tanhf(cnew);
      bool valid = t < len_b;
      float hprev = shx[j * 32 + ((b + j) & 31)];
      float hout = valid ? hnew : hprev;
      float cout = valid ? cnew : cold;
      if (half == 0) {
        c0[b * 256 + j] = cout;
        gstore(h0buf + cur * 8192 + b * 256 + j, hout);
      }
    }
    grid.sync();

    // ================= phase B: layer-1 step =================
    {
      const float* srcx = h0buf + cur * 8192;   // layer-0 output at t
      const float* srch = h1buf + prv * 8192;
      for (int i = tid; i < 8192; i += 256) {
        int bq = i >> 8, kq = i & 255;
        int a = kq * 32 + ((bq + kq) & 31);
        shx[a] = gload(srcx + i);
        shh[a] = gload(srch + i);
      }
    }
    __syncthreads();

    float s0 = 0.f, s1 = 0.f, s2 = 0.f, s3 = 0.f;
    {
      const float* Wb  = half ? Whh1 : Wih1;
      const float* hbf = half ? shh : shx;
      const float* r0 = Wb + (size_t)j * 256;
      const float* r1 = Wb + (size_t)(256 + j) * 256;
      const float* r2 = Wb + (size_t)(512 + j) * 256;
      const float* r3 = Wb + (size_t)(768 + j) * 256;
      for (int k4 = 0; k4 < 64; k4++) {
        int k = k4 * 4;
        float4 w0 = *(const float4*)(r0 + k);
        float4 w1 = *(const float4*)(r1 + k);
        float4 w2 = *(const float4*)(r2 + k);
        float4 w3 = *(const float4*)(r3 + k);
        #pragma unroll
        for (int u = 0; u < 4; u++) {
          int ku = k + u;
          float hv = hbf[ku * 32 + ((b + ku) & 31)];
          s0 += hv * ((const float*)&w0)[u];
          s1 += hv * ((const float*)&w1)[u];
          s2 += hv * ((const float*)&w2)[u];
          s3 += hv * ((const float*)&w3)[u];
        }
      }
    }
    s0 += __shfl_xor(s0, 1); s1 += __shfl_xor(s1, 1);
    s2 += __shfl_xor(s2, 1); s3 += __shfl_xor(s3, 1);

    {
      float iv = sigmoidf_(s0 + bB0);
      float fv = sigmoidf_(s1 + bB1);
      float gv = tanhf(s2 + bB2);
      float ov = sigmoidf_(s3 + bB3);
      float cold = c1[b * 256 + j];
      float cnew = fv * cold + iv * gv;
      float hnew = ov * tanhf(cnew);
      bool valid = t < len_b;
      float hprev = shh[j * 32 + ((b + j) & 31)];
      float hout = valid ? hnew : hprev;
      float cout = valid ? cnew : cold;
      if (half == 0) {
        c1[b * 256 + j] = cout;
        gstore(h1buf + cur * 8192 + b * 256 + j, hout);
      }
    }
    grid.sync();
  }

  // classifier: logits[b] = h1_last[b] . clf_w + clf_b (t=255 -> buf 1)
  if (blockIdx.x == 0 && tid < 32) {
    float s = clfb[0];
    const float* hl = h1buf + 8192 + tid * 256;
    for (int k = 0; k < 256; k++) s += gload(hl + k) * clfw[k];
    out[tid] = s;
  }
}

// ---------------------------------------------------------------------------
extern "C" void kernel_launch(void* const* d_in, const int* in_sizes, int n_in,
                              void* d_out, int out_size, void* d_ws, size_t ws_size,
                              hipStream_t stream) {
  (void)in_sizes; (void)n_in; (void)out_size; (void)ws_size;
  const float* feat = (const float*)d_in[0];
  const int*   lens = (const int*)d_in[1];
  const float* W1   = (const float*)d_in[2];
  const float* as1  = (const float*)d_in[3];
  const float* ad1  = (const float*)d_in[4];
  const float* b1   = (const float*)d_in[5];
  const float* W2   = (const float*)d_in[6];
  const float* as2  = (const float*)d_in[7];
  const float* ad2  = (const float*)d_in[8];
  const float* b2   = (const float*)d_in[9];
  const float* Wih0 = (const float*)d_in[10];
  const float* Whh0 = (const float*)d_in[11];
  const float* bih0 = (const float*)d_in[12];
  const float* bhh0 = (const float*)d_in[13];
  const float* Wih1 = (const float*)d_in[14];
  const float* Whh1 = (const float*)d_in[15];
  const float* bih1 = (const float*)d_in[16];
  const float* bhh1 = (const float*)d_in[17];
  const float* clfw = (const float*)d_in[18];
  const float* clfb = (const float*)d_in[19];

  float* ws     = (float*)d_ws;
  float* pooled = ws + 65536;   // [8192][128] -> total ws use 4.25 MB
  float* outp   = (float*)d_out;

  // zero LSTM state (cnt unused + h0/c0/h1/c1 double buffers)
  hipMemsetAsync(d_ws, 0, 65536 * sizeof(float), stream);

  gat_naive<<<8192, 256, 0, stream>>>(feat, lens, W1, as1, ad1, b1,
                                      W2, as2, ad2, b2, pooled);

  void* args[] = {
    (void*)&pooled, (void*)&Wih0, (void*)&bih0, (void*)&bhh0, (void*)&Whh0,
    (void*)&Wih1, (void*)&Whh1, (void*)&bih1, (void*)&bhh1,
    (void*)&lens, (void*)&clfw, (void*)&clfb, (void*)&ws, (void*)&outp
  };
  hipLaunchCooperativeKernel((const void*)lstm_seq, dim3(NBLK_SEQ), dim3(256),
                             args, 0, stream);
}